// Round 14
// baseline (293.217 us; speedup 1.0000x reference)
//
#include <hip/hip_runtime.h>
#include <hip/hip_bf16.h>
#include <math.h>

#define CIN 96
#define D2 192
#define D4 768
#define LL 9216
#define NN 16
#define NCH 288      /* chunks per direction */
#define CLEN 32      /* steps per chunk */

typedef float v2f __attribute__((ext_vector_type(2)));

// ---- workspace layout (float-slot offsets) ----
#define SZ_Y4SLOT (2u*2u*9216u*192u)     //  7,077,888 float slots (bf16 x2)
#define SZ_BL    (2u*9216u*192u)         //  3,538,944 (zs bf16: half used)
#define SZ_XDBL  (2u*9216u*38u)          //    700,416
#define SZ_S     (2u*4u*288u*192u)       //    442,368
#define SZ_HSLOT (2u*4u*288u*192u*8u)    //  3,538,944 float slots (bf16 x2)
#define F_Y4     0u
#define F_XX     0u                       /* alias: xx dead before y4 written */
#define F_ZS     (F_Y4 + SZ_Y4SLOT)
#define F_XT     (F_ZS + SZ_BL)
#define F_XM     (F_XT + SZ_BL)
#define F_SBUF   (F_XM + SZ_XDBL)
#define F_HBUF   (F_SBUF + SZ_S)
#define F_WCOMB  (F_HBUF + SZ_HSLOT)     /* 192*80 floats */
#define F_A0     (F_WCOMB + 15360u)      /* 768 floats */
#define F_FF     (F_A0 + 768u)           /* 768 floats */

__device__ __forceinline__ float silu_f(float z) {
    return z / (1.0f + __expf(-z));
}

// K0: fold Wx into combined padded weight; precompute a0 and fast-flag per d4
__global__ __launch_bounds__(256) void k0_foldw(
    const float* __restrict__ Wx, const float* __restrict__ Alog,
    float* __restrict__ wcomb, float* __restrict__ A0f, float* __restrict__ Ffl)
{
    int i = blockIdx.x * 256 + threadIdx.x;
    if (i < 768) {
        float a0 = -__expf(Alog[i * 16]);
        bool fast = true;
        for (int n = 1; n < 16; n++) {
            float an = -__expf(Alog[i * 16 + n]);
            float tgt = (n + 1) * a0;
            fast = fast && (fabsf(an - tgt) <= 1e-5f * fabsf(tgt));
        }
        A0f[i] = a0;
        Ffl[i] = fast ? 1.f : 0.f;
    }
    if (i >= 192 * 80) return;
    int d = i / 80, j = i % 80;
    float v = 0.f;
    if (j < 38) v = Wx[d * 38 + j] + Wx[(d + 192) * 38 + j];
    else if (j >= 40 && j < 78) {
        int jj = j - 40;
        v = Wx[(d + 384) * 38 + jj] + Wx[(d + 576) * 38 + jj];
    }
    wcomb[i] = v;
}

// K1: xz = x @ W_in + b_in. Block = 64 l x 96 e-quarter; grid 1152. zs is bf16.
__global__ __launch_bounds__(256) void k1_inproj(
    const float* __restrict__ x, const float* __restrict__ Win,
    const float* __restrict__ bin, float* __restrict__ xx,
    __hip_bfloat16* __restrict__ zs)
{
    __shared__ float xs[32][68];
    __shared__ float wsh[32][100];
    int tid = threadIdx.x;
    int bid = blockIdx.x;
    int eq = bid & 3;
    int lt = (bid >> 2) % 144;
    int b = bid / 576;
    int l0 = lt * 64;
    int e0 = eq * 96;

    int lg = tid & 15;
    int cg = tid >> 4;
    v2f acc[4][3];
#pragma unroll
    for (int i = 0; i < 4; i++)
#pragma unroll
        for (int p = 0; p < 3; p++) { acc[i][p].x = 0.f; acc[i][p].y = 0.f; }

    for (int kc = 0; kc < 96; kc += 32) {
        __syncthreads();
        for (int i = tid; i < 512; i += 256) {
            int kk = i >> 4, q = i & 15;
            float4 v = *(const float4*)&x[(size_t)(b * 96 + kc + kk) * LL + l0 + q * 4];
            *(float4*)&xs[kk][q * 4] = v;
        }
        for (int i = tid; i < 768; i += 256) {
            int kk = i / 24, q = i - kk * 24;
            float4 v = *(const float4*)&Win[(kc + kk) * 384 + e0 + q * 4];
            *(float4*)&wsh[kk][q * 4] = v;
        }
        __syncthreads();
#pragma unroll 4
        for (int k = 0; k < 32; k++) {
            float4 xv = *(const float4*)&xs[k][lg * 4];
            const v2f* wp = (const v2f*)&wsh[k][cg * 6];
            v2f w0 = wp[0], w1 = wp[1], w2 = wp[2];
            float xa[4] = {xv.x, xv.y, xv.z, xv.w};
#pragma unroll
            for (int i = 0; i < 4; i++) {
                v2f xi; xi.x = xa[i]; xi.y = xa[i];
                acc[i][0] += xi * w0;
                acc[i][1] += xi * w1;
                acc[i][2] += xi * w2;
            }
        }
    }
    if (eq < 2) {
#pragma unroll
        for (int j = 0; j < 6; j++) {
            int e = e0 + cg * 6 + j;
            float bb = bin[e];
            float4 v = {acc[0][j >> 1][j & 1] + bb, acc[1][j >> 1][j & 1] + bb,
                        acc[2][j >> 1][j & 1] + bb, acc[3][j >> 1][j & 1] + bb};
            *(float4*)&xx[(size_t)(b * 192 + e) * LL + l0 + lg * 4] = v;
        }
    } else {
        int zc0 = e0 - 192 + cg * 6;
        float bb[6];
#pragma unroll
        for (int j = 0; j < 6; j++) bb[j] = bin[e0 + cg * 6 + j];
#pragma unroll
        for (int i = 0; i < 4; i++) {
            int l = l0 + lg * 4 + i;
            __hip_bfloat16* zp = &zs[((size_t)b * LL + l) * 192 + zc0];
#pragma unroll
            for (int p = 0; p < 3; p++) {
                __hip_bfloat162 hv = __halves2bfloat162(
                    __float2bfloat16(silu_f(acc[i][p].x + bb[2 * p])),
                    __float2bfloat16(silu_f(acc[i][p].y + bb[2 * p + 1])));
                *(__hip_bfloat162*)&zp[2 * p] = hv;
            }
        }
    }
}

// K2: depthwise 3x3 conv + bias + silu, fused transpose: xx (b,192,96,96) -> xt (b,L,192)
__global__ __launch_bounds__(192) void k2_conv(
    const float* __restrict__ xx, const float* __restrict__ wdw,
    const float* __restrict__ bdw, float* __restrict__ xt)
{
    __shared__ float tile[32][97];
    __shared__ float wsm[32][9];
    __shared__ float bs[32];
    int tid = threadIdx.x;
    int bid = blockIdx.x;
    int h = bid % 96;
    int r = bid / 96;
    int dg = r % 6;
    int b = r / 6;

    for (int i = tid; i < 288; i += 192) wsm[i / 9][i % 9] = wdw[(dg * 32 + i / 9) * 9 + (i % 9)];
    if (tid < 32) bs[tid] = bdw[dg * 32 + tid];
    __syncthreads();

    int w = tid % 96;
    int dhalf = tid / 96;
    for (int p = 0; p < 16; p++) {
        int dsub = 2 * p + dhalf;
        const float* base = xx + (size_t)(b * 192 + dg * 32 + dsub) * LL;
        float acc = bs[dsub];
#pragma unroll
        for (int kh = 0; kh < 3; kh++) {
            int hh = h + kh - 1;
            if (hh < 0 || hh >= 96) continue;
            const float* row = base + hh * 96;
#pragma unroll
            for (int kw = 0; kw < 3; kw++) {
                int ww = w + kw - 1;
                if (ww < 0 || ww >= 96) continue;
                acc += row[ww] * wsm[dsub][kh * 3 + kw];
            }
        }
        tile[dsub][w] = silu_f(acc);
    }
    __syncthreads();
    for (int i = tid; i < 768; i += 192) {
        int q = i & 7, ls = i >> 3;
        float4 v = {tile[q * 4 + 0][ls], tile[q * 4 + 1][ls], tile[q * 4 + 2][ls], tile[q * 4 + 3][ls]};
        *(float4*)&xt[((size_t)b * LL + h * 96 + ls) * 192 + dg * 32 + q * 4] = v;
    }
}

// K3: direct xm writer. Block = 32 rows (la) of batch b, full K=192.
// Stages both xt[la] tile and mirror xt[LL-1-la] tile; computes fwd + rev parts;
// rev part exchanged through LDS; writes final xm[la][0:38]. Grid 576.
__global__ __launch_bounds__(320) void k3_xdbl(
    const float* __restrict__ xt, const float* __restrict__ wcomb,
    float* __restrict__ xm)
{
    __shared__ float xsf[16][36];
    __shared__ float xsr[16][36];
    __shared__ float wsh[16][80];
    __shared__ float rtile[32][40];
    int tid = threadIdx.x;
    int bid = blockIdx.x;
    int rt = bid % 288;
    int b = bid / 288;
    int r0 = rt * 32;

    int rg = tid / 20;   // 0..15 -> rows rg*2, rg*2+1
    int cg = tid % 20;   // cols cg*4..+3 of the 80-wide padded layout
    bool isf = (cg < 10);
    v2f acc[2][2];
#pragma unroll
    for (int i = 0; i < 2; i++)
#pragma unroll
        for (int p = 0; p < 2; p++) { acc[i][p].x = 0.f; acc[i][p].y = 0.f; }

    for (int kc = 0; kc < 192; kc += 16) {
        __syncthreads();
        if (tid < 128) {
            int row = tid >> 2, q = tid & 3;
            float4 v = *(const float4*)&xt[((size_t)b * LL + r0 + row) * 192 + kc + q * 4];
            xsf[q * 4 + 0][row] = v.x;
            xsf[q * 4 + 1][row] = v.y;
            xsf[q * 4 + 2][row] = v.z;
            xsf[q * 4 + 3][row] = v.w;
        } else if (tid < 256) {
            int row = (tid - 128) >> 2, q = tid & 3;
            float4 v = *(const float4*)&xt[((size_t)b * LL + (LL - 1 - r0 - row)) * 192 + kc + q * 4];
            xsr[q * 4 + 0][row] = v.x;
            xsr[q * 4 + 1][row] = v.y;
            xsr[q * 4 + 2][row] = v.z;
            xsr[q * 4 + 3][row] = v.w;
        }
        for (int i = tid; i < 1280; i += 320) {
            wsh[i / 80][i - (i / 80) * 80] = wcomb[(kc + i / 80) * 80 + (i - (i / 80) * 80)];
        }
        __syncthreads();
        const float (*xs)[36] = isf ? xsf : xsr;
#pragma unroll
        for (int d = 0; d < 16; d++) {
            float2 xv = *(const float2*)&xs[d][rg * 2];
            float4 wv = *(const float4*)&wsh[d][cg * 4];
            v2f w01; w01.x = wv.x; w01.y = wv.y;
            v2f w23; w23.x = wv.z; w23.y = wv.w;
            v2f x0; x0.x = xv.x; x0.y = xv.x;
            v2f x1; x1.x = xv.y; x1.y = xv.y;
            acc[0][0] += x0 * w01;
            acc[0][1] += x0 * w23;
            acc[1][0] += x1 * w01;
            acc[1][1] += x1 * w23;
        }
    }
    int c0 = cg * 4;
    if (!isf) {
#pragma unroll
        for (int i = 0; i < 2; i++)
#pragma unroll
            for (int j = 0; j < 4; j++)
                rtile[rg * 2 + i][c0 - 40 + j] = acc[i][j >> 1][j & 1];
    }
    __syncthreads();
    if (isf) {
#pragma unroll
        for (int i = 0; i < 2; i++) {
            int la = r0 + rg * 2 + i;
#pragma unroll
            for (int j = 0; j < 4; j++) {
                int col = c0 + j;
                if (col < 38) {
                    float v = acc[i][j >> 1][j & 1] + rtile[rg * 2 + i][col];
                    xm[((size_t)b * LL + la) * 38 + col] = v;
                }
            }
        }
    }
}

// K4 pass1: per-chunk local scan, SINGLE direction per block, h from 0.
__global__ __launch_bounds__(192, 4) void k4_pass1(
    const float* __restrict__ xt, const float* __restrict__ xm,
    const float* __restrict__ Wd, const float* __restrict__ bdl,
    const float* __restrict__ Alog, const float* __restrict__ A0f,
    const float* __restrict__ Ffl,
    float* __restrict__ Sbuf, __hip_bfloat16* __restrict__ Hbuf)
{
    __shared__ float Bt[CLEN][16];
    __shared__ float Dt[CLEN][6];
    int tid = threadIdx.x;
    int bid = blockIdx.x;
    int k = bid % NCH;
    int r = bid / NCH;
    int dir = r & 3;
    int b = r >> 2;
    int l0 = k * CLEN;
    {
        const float* src = xm + ((size_t)b * LL + l0) * 38;
        for (int i = tid; i < CLEN * 22; i += 192) {
            int t = i / 22, j = i - t * 22;
            float v = src[t * 38 + j];
            if (j < 6) Dt[t][j] = v;
            else Bt[t][j - 6] = v;
        }
    }
    __syncthreads();
    int c = tid;
    int d4 = dir * 192 + c;
    float a0 = A0f[d4];
    bool fast = (Ffl[d4] != 0.f);
    float wd[6];
#pragma unroll
    for (int rr = 0; rr < 6; rr++) wd[rr] = Wd[rr * 768 + d4];
    float bde = bdl[d4];
    float S = 0.f;
    int start = (dir < 2) ? l0 : (LL - 1 - l0);
    ptrdiff_t stp = (dir < 2) ? 192 : -192;
    const float* up = xt + (size_t)b * LL * 192 + (size_t)start * 192 + c;
    int bd = b * 4 + dir;
    size_t base = (((size_t)bd * NCH + k) * 192 + c) * 16;
    if (fast) {
        v2f h2[8];
#pragma unroll
        for (int n = 0; n < 8; n++) { h2[n].x = 0.f; h2[n].y = 0.f; }
#pragma unroll 2
        for (int t = 0; t < CLEN; t++) {
            float2 d01 = *(const float2*)&Dt[t][0];
            float2 d23 = *(const float2*)&Dt[t][2];
            float2 d45 = *(const float2*)&Dt[t][4];
            float s = bde + d01.x * wd[0] + d01.y * wd[1] + d23.x * wd[2]
                          + d23.y * wd[3] + d45.x * wd[4] + d45.y * wd[5];
            float dt = (s > 20.f) ? s : __logf(1.f + __expf(s));
            S += dt;
            float u = *up; up += stp;
            float du = dt * u;
            float e1 = __expf(dt * a0);
            float e2 = e1 * e1;
            v2f q; q.x = e1; q.y = e2;
            v2f e2v; e2v.x = e2; e2v.y = e2;
            v2f e4v = e2v * e2v;
            v2f q2 = q * e2v;
            v2f du2; du2.x = du; du2.y = du;
#pragma unroll
            for (int g = 0; g < 4; g++) {
                float4 bq = *(const float4*)&Bt[t][4 * g];
                v2f b0; b0.x = bq.x; b0.y = bq.y;
                v2f b1; b1.x = bq.z; b1.y = bq.w;
                h2[2 * g]     = q  * h2[2 * g]     + du2 * b0;
                h2[2 * g + 1] = q2 * h2[2 * g + 1] + du2 * b1;
                if (g < 3) { q *= e4v; q2 *= e4v; }
            }
        }
        __hip_bfloat16* hb = Hbuf + base;
#pragma unroll
        for (int n = 0; n < 8; n++) {
            hb[2 * n]     = __float2bfloat16(h2[n].x);
            hb[2 * n + 1] = __float2bfloat16(h2[n].y);
        }
    } else {
        float h[16];
#pragma unroll
        for (int n = 0; n < 16; n++) h[n] = 0.f;
        for (int t = 0; t < CLEN; t++) {
            float s = bde;
#pragma unroll
            for (int rr = 0; rr < 6; rr++) s += Dt[t][rr] * wd[rr];
            float dt = (s > 20.f) ? s : __logf(1.f + __expf(s));
            S += dt;
            float u = *up; up += stp;
            float du = dt * u;
#pragma unroll
            for (int n = 0; n < 16; n++) {
                float e = __expf(dt * (-__expf(Alog[d4 * 16 + n])));
                h[n] = e * h[n] + du * Bt[t][n];
            }
        }
#pragma unroll
        for (int n = 0; n < 16; n++) Hbuf[base + n] = __float2bfloat16(h[n]);
    }
    Sbuf[((size_t)bd * NCH + k) * 192 + c] = S;
}

// K4 pass2: scan over chunk summaries; Hbuf[k] := h_start (bf16); P = exp(a*S) on the fly
__global__ __launch_bounds__(256) void k4_pass2(
    const float* __restrict__ Sbuf, const float* __restrict__ Alog,
    __hip_bfloat16* __restrict__ Hbuf)
{
    int lane = blockIdx.x * 256 + threadIdx.x;  // 24576
    int bd = lane / 3072;
    int cn = lane % 3072;
    int c = cn >> 4, n = cn & 15;
    int dir = bd & 3;
    float an = -__expf(Alog[(dir * 192 + c) * 16 + n]);
    float h = 0.f;
#pragma unroll 8
    for (int k = 0; k < NCH; k++) {
        size_t sidx = ((size_t)bd * NCH + k) * 192 + c;
        float S = Sbuf[sidx];
        size_t idx = sidx * 16 + n;
        float hl = __bfloat162float(Hbuf[idx]);
        float P = __expf(an * S);
        Hbuf[idx] = __float2bfloat16(h);
        h = P * h + hl;
    }
}

// K4 pass3: replay chunk from h_start; y -> bf16 slab. Running-multiplier fast path.
__global__ __launch_bounds__(192, 4) void k4_pass3(
    const float* __restrict__ xt, const float* __restrict__ xm,
    const float* __restrict__ Wd, const float* __restrict__ bdl,
    const float* __restrict__ Alog, const float* __restrict__ A0f,
    const float* __restrict__ Ffl, const float* __restrict__ Dp,
    const __hip_bfloat16* __restrict__ Hbuf, __hip_bfloat16* __restrict__ y4)
{
    __shared__ float Bt[CLEN][16];
    __shared__ float Ct[CLEN][16];
    __shared__ float Dt[CLEN][6];
    int tid = threadIdx.x;
    int bid = blockIdx.x;
    int k = bid % NCH;
    int r = bid / NCH;
    int dir = r & 3;
    int b = r >> 2;
    int l0 = k * CLEN;
    {
        const float* src = xm + ((size_t)b * LL + l0) * 38;
        for (int i = tid; i < CLEN * 38; i += 192) {
            int t = i / 38, j = i - t * 38;
            float v = src[i];
            if (j < 6) Dt[t][j] = v;
            else if (j < 22) Bt[t][j - 6] = v;
            else Ct[t][j - 22] = v;
        }
    }
    __syncthreads();
    int c = tid;
    int d4 = dir * 192 + c;
    float a0 = A0f[d4];
    bool fast = (Ffl[d4] != 0.f);
    float wd[6];
#pragma unroll
    for (int rr = 0; rr < 6; rr++) wd[rr] = Wd[rr * 768 + d4];
    float bde = bdl[d4];
    float Dv = Dp[d4];
    int bd = b * 4 + dir;
    size_t base = (((size_t)bd * NCH + k) * 192 + c) * 16;
    int start = (dir < 2) ? l0 : (LL - 1 - l0);
    ptrdiff_t stp = (dir < 2) ? 192 : -192;
    const float* up = xt + (size_t)b * LL * 192 + (size_t)start * 192 + c;
    __hip_bfloat16* yp = y4 + (size_t)bd * LL * 192 + (size_t)start * 192 + c;
    if (fast) {
        v2f h2[8];
        const __hip_bfloat16* hb = Hbuf + base;
#pragma unroll
        for (int n = 0; n < 8; n++) {
            h2[n].x = __bfloat162float(hb[2 * n]);
            h2[n].y = __bfloat162float(hb[2 * n + 1]);
        }
#pragma unroll 2
        for (int t = 0; t < CLEN; t++) {
            float2 d01 = *(const float2*)&Dt[t][0];
            float2 d23 = *(const float2*)&Dt[t][2];
            float2 d45 = *(const float2*)&Dt[t][4];
            float s = bde + d01.x * wd[0] + d01.y * wd[1] + d23.x * wd[2]
                          + d23.y * wd[3] + d45.x * wd[4] + d45.y * wd[5];
            float dt = (s > 20.f) ? s : __logf(1.f + __expf(s));
            float u = *up; up += stp;
            float du = dt * u;
            float e1 = __expf(dt * a0);
            float e2 = e1 * e1;
            v2f q; q.x = e1; q.y = e2;
            v2f e2v; e2v.x = e2; e2v.y = e2;
            v2f e4v = e2v * e2v;
            v2f q2 = q * e2v;
            v2f du2; du2.x = du; du2.y = du;
            v2f ya; ya.x = 0.f; ya.y = 0.f;
            v2f yb; yb.x = 0.f; yb.y = 0.f;
#pragma unroll
            for (int g = 0; g < 4; g++) {
                float4 bq = *(const float4*)&Bt[t][4 * g];
                float4 cq = *(const float4*)&Ct[t][4 * g];
                v2f b0; b0.x = bq.x; b0.y = bq.y;
                v2f b1; b1.x = bq.z; b1.y = bq.w;
                v2f c0v; c0v.x = cq.x; c0v.y = cq.y;
                v2f c1v; c1v.x = cq.z; c1v.y = cq.w;
                h2[2 * g]     = q  * h2[2 * g]     + du2 * b0;
                ya += h2[2 * g] * c0v;
                h2[2 * g + 1] = q2 * h2[2 * g + 1] + du2 * b1;
                yb += h2[2 * g + 1] * c1v;
                if (g < 3) { q *= e4v; q2 *= e4v; }
            }
            float yv = (ya.x + ya.y) + (yb.x + yb.y) + Dv * u;
            *yp = __float2bfloat16(yv); yp += stp;
        }
    } else {
        float h[16];
#pragma unroll
        for (int n = 0; n < 16; n++) h[n] = __bfloat162float(Hbuf[base + n]);
        for (int t = 0; t < CLEN; t++) {
            float s = bde;
#pragma unroll
            for (int rr = 0; rr < 6; rr++) s += Dt[t][rr] * wd[rr];
            float dt = (s > 20.f) ? s : __logf(1.f + __expf(s));
            float u = *up; up += stp;
            float du = dt * u;
            float yv = Dv * u;
#pragma unroll
            for (int n = 0; n < 16; n++) {
                float e = __expf(dt * (-__expf(Alog[d4 * 16 + n])));
                h[n] = e * h[n] + du * Bt[t][n];
                yv += h[n] * Ct[t][n];
            }
            *yp = __float2bfloat16(yv); yp += stp;
        }
    }
}

// K5: yh = sum of 4 bf16 slabs; LayerNorm(192); * silu(z) (bf16); @ W_out -> out (b,96,H,W)
// bf162 pair loads for y4/zs.
__global__ __launch_bounds__(256) void k5_out(
    const __hip_bfloat16* __restrict__ y4, const __hip_bfloat16* __restrict__ zs,
    const float* __restrict__ lng, const float* __restrict__ lnb,
    const float* __restrict__ Wout, float* __restrict__ out)
{
    __shared__ float acts[16][196];
    __shared__ float wsh[32][100];
    int tid = threadIdx.x;
    int wv = tid >> 6;
    int lane = tid & 63;
    int gl0 = blockIdx.x * 16;
    int b = gl0 / LL;
    int l0 = gl0 % LL;
    const size_t ds = (size_t)LL * 192;

    for (int i = 0; i < 4; i++) {
        int rrow = wv * 4 + i;
        int l = l0 + rrow;
        float ypr[2][2], zpr[2][2];
        float s1 = 0.f, s2 = 0.f;
#pragma unroll
        for (int kk = 0; kk < 2; kk++) {
            int pair = kk * 64 + lane;
            bool act = (kk == 0) || (lane < 32);
            float y0 = 0.f, y1 = 0.f, z0 = 0.f, z1 = 0.f;
            if (act) {
                int cbase = pair * 2;
                size_t off = ((size_t)(b * 4) * LL + l) * 192 + cbase;
                __hip_bfloat162 v0 = *(const __hip_bfloat162*)&y4[off];
                __hip_bfloat162 v1 = *(const __hip_bfloat162*)&y4[off + ds];
                __hip_bfloat162 v2 = *(const __hip_bfloat162*)&y4[off + 2 * ds];
                __hip_bfloat162 v3 = *(const __hip_bfloat162*)&y4[off + 3 * ds];
                y0 = __bfloat162float(v0.x) + __bfloat162float(v1.x)
                   + __bfloat162float(v2.x) + __bfloat162float(v3.x);
                y1 = __bfloat162float(v0.y) + __bfloat162float(v1.y)
                   + __bfloat162float(v2.y) + __bfloat162float(v3.y);
                __hip_bfloat162 zv = *(const __hip_bfloat162*)&zs[((size_t)b * LL + l) * 192 + cbase];
                z0 = __bfloat162float(zv.x);
                z1 = __bfloat162float(zv.y);
                s1 += y0 + y1;
                s2 += y0 * y0 + y1 * y1;
            }
            ypr[kk][0] = y0; ypr[kk][1] = y1;
            zpr[kk][0] = z0; zpr[kk][1] = z1;
        }
#pragma unroll
        for (int o = 32; o; o >>= 1) {
            s1 += __shfl_xor(s1, o, 64);
            s2 += __shfl_xor(s2, o, 64);
        }
        float mean = s1 * (1.f / 192.f);
        float var = s2 * (1.f / 192.f) - mean * mean;
        float rs = rsqrtf(var + 1e-5f);
#pragma unroll
        for (int kk = 0; kk < 2; kk++) {
            bool act = (kk == 0) || (lane < 32);
            if (act) {
                int cbase = (kk * 64 + lane) * 2;
#pragma unroll
                for (int p = 0; p < 2; p++) {
                    int cc = cbase + p;
                    float yn = (ypr[kk][p] - mean) * rs * lng[cc] + lnb[cc];
                    acts[rrow][cc] = yn * zpr[kk][p];
                }
            }
        }
    }

    int ty = tid & 15;
    int tx = tid >> 4;
    v2f o2[3];
    o2[0].x = 0.f; o2[0].y = 0.f;
    o2[1].x = 0.f; o2[1].y = 0.f;
    o2[2].x = 0.f; o2[2].y = 0.f;

    for (int kc = 0; kc < 192; kc += 32) {
        __syncthreads();
        for (int i = tid; i < 32 * 24; i += 256) {
            int d = i / 24, q = i - d * 24;
            *(float4*)&wsh[d][q * 4] = *(const float4*)&Wout[(kc + d) * 96 + q * 4];
        }
        __syncthreads();
#pragma unroll
        for (int kk = 0; kk < 32; kk++) {
            float av = acts[ty][kc + kk];
            const v2f* wp = (const v2f*)&wsh[kk][tx * 6];
            v2f w0 = wp[0], w1 = wp[1], w2 = wp[2];
            v2f sp; sp.x = av; sp.y = av;
            o2[0] += sp * w0;
            o2[1] += sp * w1;
            o2[2] += sp * w2;
        }
    }
    int l = l0 + ty;
#pragma unroll
    for (int j = 0; j < 6; j++) {
        int n = tx * 6 + j;
        out[((size_t)(b * 96) + n) * LL + l] = o2[j >> 1][j & 1];
    }
}

extern "C" void kernel_launch(void* const* d_in, const int* in_sizes, int n_in,
                              void* d_out, int out_size, void* d_ws, size_t ws_size,
                              hipStream_t stream)
{
    const float* x    = (const float*)d_in[0];
    const float* Win  = (const float*)d_in[1];
    const float* bin  = (const float*)d_in[2];
    const float* wdw  = (const float*)d_in[3];
    const float* bdw  = (const float*)d_in[4];
    const float* Alog = (const float*)d_in[5];
    const float* Dp   = (const float*)d_in[6];
    const float* Wx   = (const float*)d_in[7];
    const float* Wd   = (const float*)d_in[8];
    const float* bdl  = (const float*)d_in[9];
    const float* lng  = (const float*)d_in[10];
    const float* lnb  = (const float*)d_in[11];
    const float* Wout = (const float*)d_in[12];
    float* out = (float*)d_out;

    float* ws    = (float*)d_ws;
    __hip_bfloat16* y4 = (__hip_bfloat16*)(ws + F_Y4);
    float* xx    = ws + F_XX;    // aliases y4 slab region (dead before y4 written)
    __hip_bfloat16* zs = (__hip_bfloat16*)(ws + F_ZS);
    float* xt    = ws + F_XT;
    float* xm    = ws + F_XM;
    float* Sbuf  = ws + F_SBUF;
    __hip_bfloat16* Hbuf = (__hip_bfloat16*)(ws + F_HBUF);
    float* wcomb = ws + F_WCOMB;
    float* A0f   = ws + F_A0;
    float* Ffl   = ws + F_FF;

    k0_foldw<<<60, 256, 0, stream>>>(Wx, Alog, wcomb, A0f, Ffl);
    k1_inproj<<<1152, 256, 0, stream>>>(x, Win, bin, xx, zs);
    k2_conv<<<1152, 192, 0, stream>>>(xx, wdw, bdw, xt);
    k3_xdbl<<<576, 320, 0, stream>>>(xt, wcomb, xm);
    k4_pass1<<<2304, 192, 0, stream>>>(xt, xm, Wd, bdl, Alog, A0f, Ffl, Sbuf, Hbuf);
    k4_pass2<<<96, 256, 0, stream>>>(Sbuf, Alog, Hbuf);
    k4_pass3<<<2304, 192, 0, stream>>>(xt, xm, Wd, bdl, Alog, A0f, Ffl, Dp, Hbuf, y4);
    k5_out<<<1152, 256, 0, stream>>>(y4, zs, lng, lnb, Wout, out);
}

// Round 15
// 284.191 us; speedup vs baseline: 1.0318x; 1.0318x over previous
//
#include <hip/hip_runtime.h>
#include <hip/hip_bf16.h>
#include <math.h>

#define CIN 96
#define D2 192
#define D4 768
#define LL 9216
#define NN 16
#define NCH 288      /* chunks per direction */
#define CLEN 32      /* steps per chunk */

typedef float v2f __attribute__((ext_vector_type(2)));

// ---- workspace layout (float-slot offsets) ----
#define SZ_Y4SLOT (2u*2u*9216u*192u)     //  7,077,888 float slots (bf16 x2)
#define SZ_BL    (2u*9216u*192u)         //  3,538,944 (zs bf16: half used)
#define SZ_XDBL  (2u*9216u*38u)          //    700,416
#define SZ_S     (2u*4u*288u*192u)       //    442,368
#define SZ_HSLOT (2u*4u*288u*192u*8u)    //  3,538,944 float slots (bf16 x2)
#define F_Y4     0u
#define F_XX     0u                       /* alias: xx dead before y4 written */
#define F_ZS     (F_Y4 + SZ_Y4SLOT)
#define F_XT     (F_ZS + SZ_BL)
#define F_XD0    (F_XT + SZ_BL)
#define F_XD1    (F_XD0 + SZ_XDBL)
#define F_XD2    (F_XD1 + SZ_XDBL)
#define F_XD3    (F_XD2 + SZ_XDBL)
#define F_SBUF   (F_XD3 + SZ_XDBL)
#define F_HBUF   (F_SBUF + SZ_S)
#define F_WCOMB  (F_HBUF + SZ_HSLOT)     /* 192*80 floats */
#define F_A0     (F_WCOMB + 15360u)      /* 768 floats */
#define F_FF     (F_A0 + 768u)           /* 768 floats */

__device__ __forceinline__ float silu_f(float z) {
    return z / (1.0f + __expf(-z));
}

// K1: xz = x @ W_in + b_in. Block = 64 l x 96 e-quarter; grid 1152. zs is bf16.
// Blocks < 60 additionally run the former k0 preamble (wcomb fold + A0f/Ffl).
__global__ __launch_bounds__(256) void k1_inproj(
    const float* __restrict__ x, const float* __restrict__ Win,
    const float* __restrict__ bin, const float* __restrict__ Wx,
    const float* __restrict__ Alog, float* __restrict__ wcomb,
    float* __restrict__ A0f, float* __restrict__ Ffl,
    float* __restrict__ xx, __hip_bfloat16* __restrict__ zs)
{
    __shared__ float xs[32][68];
    __shared__ float wsh[32][100];
    int tid = threadIdx.x;
    int bid = blockIdx.x;

    if (bid < 60) {
        int i = bid * 256 + tid;
        if (i < 768) {
            float a0 = -__expf(Alog[i * 16]);
            bool fast = true;
            for (int n = 1; n < 16; n++) {
                float an = -__expf(Alog[i * 16 + n]);
                float tgt = (n + 1) * a0;
                fast = fast && (fabsf(an - tgt) <= 1e-5f * fabsf(tgt));
            }
            A0f[i] = a0;
            Ffl[i] = fast ? 1.f : 0.f;
        }
        int d = i / 80, j = i % 80;
        float v = 0.f;
        if (j < 38) v = Wx[d * 38 + j] + Wx[(d + 192) * 38 + j];
        else if (j >= 40 && j < 78) {
            int jj = j - 40;
            v = Wx[(d + 384) * 38 + jj] + Wx[(d + 576) * 38 + jj];
        }
        wcomb[i] = v;
    }

    int eq = bid & 3;
    int lt = (bid >> 2) % 144;
    int b = bid / 576;
    int l0 = lt * 64;
    int e0 = eq * 96;

    int lg = tid & 15;
    int cg = tid >> 4;
    v2f acc[4][3];
#pragma unroll
    for (int i = 0; i < 4; i++)
#pragma unroll
        for (int p = 0; p < 3; p++) { acc[i][p].x = 0.f; acc[i][p].y = 0.f; }

    for (int kc = 0; kc < 96; kc += 32) {
        __syncthreads();
        for (int i = tid; i < 512; i += 256) {
            int kk = i >> 4, q = i & 15;
            float4 v = *(const float4*)&x[(size_t)(b * 96 + kc + kk) * LL + l0 + q * 4];
            *(float4*)&xs[kk][q * 4] = v;
        }
        for (int i = tid; i < 768; i += 256) {
            int kk = i / 24, q = i - kk * 24;
            float4 v = *(const float4*)&Win[(kc + kk) * 384 + e0 + q * 4];
            *(float4*)&wsh[kk][q * 4] = v;
        }
        __syncthreads();
#pragma unroll 4
        for (int k = 0; k < 32; k++) {
            float4 xv = *(const float4*)&xs[k][lg * 4];
            const v2f* wp = (const v2f*)&wsh[k][cg * 6];
            v2f w0 = wp[0], w1 = wp[1], w2 = wp[2];
            float xa[4] = {xv.x, xv.y, xv.z, xv.w};
#pragma unroll
            for (int i = 0; i < 4; i++) {
                v2f xi; xi.x = xa[i]; xi.y = xa[i];
                acc[i][0] += xi * w0;
                acc[i][1] += xi * w1;
                acc[i][2] += xi * w2;
            }
        }
    }
    if (eq < 2) {
#pragma unroll
        for (int j = 0; j < 6; j++) {
            int e = e0 + cg * 6 + j;
            float bb = bin[e];
            float4 v = {acc[0][j >> 1][j & 1] + bb, acc[1][j >> 1][j & 1] + bb,
                        acc[2][j >> 1][j & 1] + bb, acc[3][j >> 1][j & 1] + bb};
            *(float4*)&xx[(size_t)(b * 192 + e) * LL + l0 + lg * 4] = v;
        }
    } else {
        int zc0 = e0 - 192 + cg * 6;
        float bb[6];
#pragma unroll
        for (int j = 0; j < 6; j++) bb[j] = bin[e0 + cg * 6 + j];
#pragma unroll
        for (int i = 0; i < 4; i++) {
            int l = l0 + lg * 4 + i;
            __hip_bfloat16* zp = &zs[((size_t)b * LL + l) * 192 + zc0];
#pragma unroll
            for (int p = 0; p < 3; p++) {
                __hip_bfloat162 hv = __halves2bfloat162(
                    __float2bfloat16(silu_f(acc[i][p].x + bb[2 * p])),
                    __float2bfloat16(silu_f(acc[i][p].y + bb[2 * p + 1])));
                *(__hip_bfloat162*)&zp[2 * p] = hv;
            }
        }
    }
}

// K2: depthwise 3x3 conv + bias + silu, fused transpose: xx (b,192,96,96) -> xt (b,L,192)
__global__ __launch_bounds__(192) void k2_conv(
    const float* __restrict__ xx, const float* __restrict__ wdw,
    const float* __restrict__ bdw, float* __restrict__ xt)
{
    __shared__ float tile[32][97];
    __shared__ float wsm[32][9];
    __shared__ float bs[32];
    int tid = threadIdx.x;
    int bid = blockIdx.x;
    int h = bid % 96;
    int r = bid / 96;
    int dg = r % 6;
    int b = r / 6;

    for (int i = tid; i < 288; i += 192) wsm[i / 9][i % 9] = wdw[(dg * 32 + i / 9) * 9 + (i % 9)];
    if (tid < 32) bs[tid] = bdw[dg * 32 + tid];
    __syncthreads();

    int w = tid % 96;
    int dhalf = tid / 96;
    for (int p = 0; p < 16; p++) {
        int dsub = 2 * p + dhalf;
        const float* base = xx + (size_t)(b * 192 + dg * 32 + dsub) * LL;
        float acc = bs[dsub];
#pragma unroll
        for (int kh = 0; kh < 3; kh++) {
            int hh = h + kh - 1;
            if (hh < 0 || hh >= 96) continue;
            const float* row = base + hh * 96;
#pragma unroll
            for (int kw = 0; kw < 3; kw++) {
                int ww = w + kw - 1;
                if (ww < 0 || ww >= 96) continue;
                acc += row[ww] * wsm[dsub][kh * 3 + kw];
            }
        }
        tile[dsub][w] = silu_f(acc);
    }
    __syncthreads();
    for (int i = tid; i < 768; i += 192) {
        int q = i & 7, ls = i >> 3;
        float4 v = {tile[q * 4 + 0][ls], tile[q * 4 + 1][ls], tile[q * 4 + 2][ls], tile[q * 4 + 3][ls]};
        *(float4*)&xt[((size_t)b * LL + h * 96 + ls) * 192 + dg * 32 + q * 4] = v;
    }
}

// K3: GEMM  out[64 rows x 80 cols] = X[64x96(khalf)] @ Wcomb[96x80], K-split over 2 blocks.
__global__ __launch_bounds__(320) void k3_xdbl(
    const float* __restrict__ xt, const float* __restrict__ wcomb,
    float* __restrict__ xa0, float* __restrict__ xa1,
    float* __restrict__ xb0, float* __restrict__ xb1)
{
    __shared__ float xs[16][68];
    __shared__ float wsh[16][80];
    int tid = threadIdx.x;
    int bid = blockIdx.x;
    int kh = bid & 1;
    int rt = (bid >> 1) % 144;
    int b = bid / 288;
    int r0 = rt * 64;
    int k0 = kh * 96;
    float* __restrict__ xa = kh ? xa1 : xa0;
    float* __restrict__ xb = kh ? xb1 : xb0;

    int rg = tid / 20;
    int cg = tid % 20;
    v2f acc[4][2];
#pragma unroll
    for (int i = 0; i < 4; i++)
#pragma unroll
        for (int p = 0; p < 2; p++) { acc[i][p].x = 0.f; acc[i][p].y = 0.f; }

    for (int kc = 0; kc < 96; kc += 16) {
        __syncthreads();
        if (tid < 256) {
            int row = tid >> 2, dq = tid & 3;
            float4 v = *(const float4*)&xt[((size_t)b * LL + r0 + row) * 192 + k0 + kc + dq * 4];
            xs[dq * 4 + 0][row] = v.x;
            xs[dq * 4 + 1][row] = v.y;
            xs[dq * 4 + 2][row] = v.z;
            xs[dq * 4 + 3][row] = v.w;
        }
        for (int i = tid; i < 16 * 80; i += 320) {
            int d = i / 80, j = i - d * 80;
            wsh[d][j] = wcomb[(k0 + kc + d) * 80 + j];
        }
        __syncthreads();
#pragma unroll
        for (int d = 0; d < 16; d++) {
            float4 xv = *(const float4*)&xs[d][rg * 4];
            float4 wv = *(const float4*)&wsh[d][cg * 4];
            v2f w01; w01.x = wv.x; w01.y = wv.y;
            v2f w23; w23.x = wv.z; w23.y = wv.w;
            float xr[4] = {xv.x, xv.y, xv.z, xv.w};
#pragma unroll
            for (int i = 0; i < 4; i++) {
                v2f xi; xi.x = xr[i]; xi.y = xr[i];
                acc[i][0] += xi * w01;
                acc[i][1] += xi * w23;
            }
        }
    }
    int c0 = cg * 4;
#pragma unroll
    for (int i = 0; i < 4; i++) {
        int la = r0 + rg * 4 + i;
#pragma unroll
        for (int j = 0; j < 4; j++) {
            int col = c0 + j;
            float v = acc[i][j >> 1][j & 1];
            if (col < 38) {
                xa[((size_t)b * LL + la) * 38 + col] = v;
            } else if (col >= 40 && col < 78) {
                int lb = LL - 1 - la;
                xb[((size_t)b * LL + lb) * 38 + (col - 40)] = v;
            }
        }
    }
}

// K4 pass1: per-chunk local scan, SINGLE direction per block, h from 0.
__global__ __launch_bounds__(192, 4) void k4_pass1(
    const float* __restrict__ xt,
    const float* __restrict__ xa0, const float* __restrict__ xa1,
    const float* __restrict__ xb0, const float* __restrict__ xb1,
    const float* __restrict__ Wd, const float* __restrict__ bdl,
    const float* __restrict__ Alog, const float* __restrict__ A0f,
    const float* __restrict__ Ffl,
    float* __restrict__ Sbuf, __hip_bfloat16* __restrict__ Hbuf)
{
    __shared__ float Bt[CLEN][16];
    __shared__ float Dt[CLEN][6];
    int tid = threadIdx.x;
    int bid = blockIdx.x;
    int k = bid % NCH;
    int r = bid / NCH;
    int dir = r & 3;
    int b = r >> 2;
    int l0 = k * CLEN;
    for (int i = tid; i < CLEN * 16; i += 192) {
        int t = i >> 4, n = i & 15;
        size_t rb = ((size_t)b * LL + l0 + t) * 38 + 6 + n;
        Bt[t][n] = (xa0[rb] + xa1[rb]) + (xb0[rb] + xb1[rb]);
    }
    for (int i = tid; i < CLEN * 6; i += 192) {
        int t = i / 6, rr = i - 6 * t;
        size_t rb = ((size_t)b * LL + l0 + t) * 38 + rr;
        Dt[t][rr] = (xa0[rb] + xa1[rb]) + (xb0[rb] + xb1[rb]);
    }
    __syncthreads();
    int c = tid;
    int d4 = dir * 192 + c;
    float a0 = A0f[d4];
    bool fast = (Ffl[d4] != 0.f);
    float wd[6];
#pragma unroll
    for (int rr = 0; rr < 6; rr++) wd[rr] = Wd[rr * 768 + d4];
    float bde = bdl[d4];
    float S = 0.f;
    int start = (dir < 2) ? l0 : (LL - 1 - l0);
    ptrdiff_t stp = (dir < 2) ? 192 : -192;
    const float* up = xt + (size_t)b * LL * 192 + (size_t)start * 192 + c;
    int bd = b * 4 + dir;
    size_t base = (((size_t)bd * NCH + k) * 192 + c) * 16;
    if (fast) {
        v2f h2[8];
#pragma unroll
        for (int n = 0; n < 8; n++) { h2[n].x = 0.f; h2[n].y = 0.f; }
#pragma unroll 2
        for (int t = 0; t < CLEN; t++) {
            float2 d01 = *(const float2*)&Dt[t][0];
            float2 d23 = *(const float2*)&Dt[t][2];
            float2 d45 = *(const float2*)&Dt[t][4];
            float s = bde + d01.x * wd[0] + d01.y * wd[1] + d23.x * wd[2]
                          + d23.y * wd[3] + d45.x * wd[4] + d45.y * wd[5];
            float dt = (s > 20.f) ? s : __logf(1.f + __expf(s));
            S += dt;
            float u = *up; up += stp;
            float du = dt * u;
            float e1 = __expf(dt * a0);
            float e2 = e1 * e1;
            v2f q; q.x = e1; q.y = e2;
            v2f e2v; e2v.x = e2; e2v.y = e2;
            v2f e4v = e2v * e2v;
            v2f q2 = q * e2v;
            v2f du2; du2.x = du; du2.y = du;
#pragma unroll
            for (int g = 0; g < 4; g++) {
                float4 bq = *(const float4*)&Bt[t][4 * g];
                v2f b0; b0.x = bq.x; b0.y = bq.y;
                v2f b1; b1.x = bq.z; b1.y = bq.w;
                h2[2 * g]     = q  * h2[2 * g]     + du2 * b0;
                h2[2 * g + 1] = q2 * h2[2 * g + 1] + du2 * b1;
                if (g < 3) { q *= e4v; q2 *= e4v; }
            }
        }
        __hip_bfloat16* hb = Hbuf + base;
#pragma unroll
        for (int n = 0; n < 8; n++) {
            hb[2 * n]     = __float2bfloat16(h2[n].x);
            hb[2 * n + 1] = __float2bfloat16(h2[n].y);
        }
    } else {
        float h[16];
#pragma unroll
        for (int n = 0; n < 16; n++) h[n] = 0.f;
        for (int t = 0; t < CLEN; t++) {
            float s = bde;
#pragma unroll
            for (int rr = 0; rr < 6; rr++) s += Dt[t][rr] * wd[rr];
            float dt = (s > 20.f) ? s : __logf(1.f + __expf(s));
            S += dt;
            float u = *up; up += stp;
            float du = dt * u;
#pragma unroll
            for (int n = 0; n < 16; n++) {
                float e = __expf(dt * (-__expf(Alog[d4 * 16 + n])));
                h[n] = e * h[n] + du * Bt[t][n];
            }
        }
#pragma unroll
        for (int n = 0; n < 16; n++) Hbuf[base + n] = __float2bfloat16(h[n]);
    }
    Sbuf[((size_t)bd * NCH + k) * 192 + c] = S;
}

// K4 pass2: scan over chunk summaries; Hbuf[k] := h_start (bf16); P = exp(a*S) on the fly
__global__ __launch_bounds__(256) void k4_pass2(
    const float* __restrict__ Sbuf, const float* __restrict__ Alog,
    __hip_bfloat16* __restrict__ Hbuf)
{
    int lane = blockIdx.x * 256 + threadIdx.x;  // 24576
    int bd = lane / 3072;
    int cn = lane % 3072;
    int c = cn >> 4, n = cn & 15;
    int dir = bd & 3;
    float an = -__expf(Alog[(dir * 192 + c) * 16 + n]);
    float h = 0.f;
#pragma unroll 8
    for (int k = 0; k < NCH; k++) {
        size_t sidx = ((size_t)bd * NCH + k) * 192 + c;
        float S = Sbuf[sidx];
        size_t idx = sidx * 16 + n;
        float hl = __bfloat162float(Hbuf[idx]);
        float P = __expf(an * S);
        Hbuf[idx] = __float2bfloat16(h);
        h = P * h + hl;
    }
}

// K4 pass3: replay chunk from h_start; y -> bf16 slab. Running-multiplier fast path.
__global__ __launch_bounds__(192, 4) void k4_pass3(
    const float* __restrict__ xt,
    const float* __restrict__ xa0, const float* __restrict__ xa1,
    const float* __restrict__ xb0, const float* __restrict__ xb1,
    const float* __restrict__ Wd, const float* __restrict__ bdl,
    const float* __restrict__ Alog, const float* __restrict__ A0f,
    const float* __restrict__ Ffl, const float* __restrict__ Dp,
    const __hip_bfloat16* __restrict__ Hbuf, __hip_bfloat16* __restrict__ y4)
{
    __shared__ float Bt[CLEN][16];
    __shared__ float Ct[CLEN][16];
    __shared__ float Dt[CLEN][6];
    int tid = threadIdx.x;
    int bid = blockIdx.x;
    int k = bid % NCH;
    int r = bid / NCH;
    int dir = r & 3;
    int b = r >> 2;
    int l0 = k * CLEN;
    for (int i = tid; i < CLEN * 16; i += 192) {
        int t = i >> 4, n = i & 15;
        size_t rb = ((size_t)b * LL + l0 + t) * 38;
        size_t r1 = rb + 6 + n, r2 = rb + 22 + n;
        Bt[t][n] = (xa0[r1] + xa1[r1]) + (xb0[r1] + xb1[r1]);
        Ct[t][n] = (xa0[r2] + xa1[r2]) + (xb0[r2] + xb1[r2]);
    }
    for (int i = tid; i < CLEN * 6; i += 192) {
        int t = i / 6, rr = i - 6 * t;
        size_t rb = ((size_t)b * LL + l0 + t) * 38 + rr;
        Dt[t][rr] = (xa0[rb] + xa1[rb]) + (xb0[rb] + xb1[rb]);
    }
    __syncthreads();
    int c = tid;
    int d4 = dir * 192 + c;
    float a0 = A0f[d4];
    bool fast = (Ffl[d4] != 0.f);
    float wd[6];
#pragma unroll
    for (int rr = 0; rr < 6; rr++) wd[rr] = Wd[rr * 768 + d4];
    float bde = bdl[d4];
    float Dv = Dp[d4];
    int bd = b * 4 + dir;
    size_t base = (((size_t)bd * NCH + k) * 192 + c) * 16;
    int start = (dir < 2) ? l0 : (LL - 1 - l0);
    ptrdiff_t stp = (dir < 2) ? 192 : -192;
    const float* up = xt + (size_t)b * LL * 192 + (size_t)start * 192 + c;
    __hip_bfloat16* yp = y4 + (size_t)bd * LL * 192 + (size_t)start * 192 + c;
    if (fast) {
        v2f h2[8];
        const __hip_bfloat16* hb = Hbuf + base;
#pragma unroll
        for (int n = 0; n < 8; n++) {
            h2[n].x = __bfloat162float(hb[2 * n]);
            h2[n].y = __bfloat162float(hb[2 * n + 1]);
        }
#pragma unroll 2
        for (int t = 0; t < CLEN; t++) {
            float2 d01 = *(const float2*)&Dt[t][0];
            float2 d23 = *(const float2*)&Dt[t][2];
            float2 d45 = *(const float2*)&Dt[t][4];
            float s = bde + d01.x * wd[0] + d01.y * wd[1] + d23.x * wd[2]
                          + d23.y * wd[3] + d45.x * wd[4] + d45.y * wd[5];
            float dt = (s > 20.f) ? s : __logf(1.f + __expf(s));
            float u = *up; up += stp;
            float du = dt * u;
            float e1 = __expf(dt * a0);
            float e2 = e1 * e1;
            v2f q; q.x = e1; q.y = e2;
            v2f e2v; e2v.x = e2; e2v.y = e2;
            v2f e4v = e2v * e2v;
            v2f q2 = q * e2v;
            v2f du2; du2.x = du; du2.y = du;
            v2f ya; ya.x = 0.f; ya.y = 0.f;
            v2f yb; yb.x = 0.f; yb.y = 0.f;
#pragma unroll
            for (int g = 0; g < 4; g++) {
                float4 bq = *(const float4*)&Bt[t][4 * g];
                float4 cq = *(const float4*)&Ct[t][4 * g];
                v2f b0; b0.x = bq.x; b0.y = bq.y;
                v2f b1; b1.x = bq.z; b1.y = bq.w;
                v2f c0v; c0v.x = cq.x; c0v.y = cq.y;
                v2f c1v; c1v.x = cq.z; c1v.y = cq.w;
                h2[2 * g]     = q  * h2[2 * g]     + du2 * b0;
                ya += h2[2 * g] * c0v;
                h2[2 * g + 1] = q2 * h2[2 * g + 1] + du2 * b1;
                yb += h2[2 * g + 1] * c1v;
                if (g < 3) { q *= e4v; q2 *= e4v; }
            }
            float yv = (ya.x + ya.y) + (yb.x + yb.y) + Dv * u;
            *yp = __float2bfloat16(yv); yp += stp;
        }
    } else {
        float h[16];
#pragma unroll
        for (int n = 0; n < 16; n++) h[n] = __bfloat162float(Hbuf[base + n]);
        for (int t = 0; t < CLEN; t++) {
            float s = bde;
#pragma unroll
            for (int rr = 0; rr < 6; rr++) s += Dt[t][rr] * wd[rr];
            float dt = (s > 20.f) ? s : __logf(1.f + __expf(s));
            float u = *up; up += stp;
            float du = dt * u;
            float yv = Dv * u;
#pragma unroll
            for (int n = 0; n < 16; n++) {
                float e = __expf(dt * (-__expf(Alog[d4 * 16 + n])));
                h[n] = e * h[n] + du * Bt[t][n];
                yv += h[n] * Ct[t][n];
            }
            *yp = __float2bfloat16(yv); yp += stp;
        }
    }
}

// K5: yh = sum of 4 bf16 slabs; LayerNorm(192); * silu(z) (bf16); @ W_out -> out (b,96,H,W)
__global__ __launch_bounds__(256) void k5_out(
    const __hip_bfloat16* __restrict__ y4, const __hip_bfloat16* __restrict__ zs,
    const float* __restrict__ lng, const float* __restrict__ lnb,
    const float* __restrict__ Wout, float* __restrict__ out)
{
    __shared__ float acts[16][196];
    __shared__ float wsh[32][100];
    int tid = threadIdx.x;
    int wv = tid >> 6;
    int lane = tid & 63;
    int gl0 = blockIdx.x * 16;
    int b = gl0 / LL;
    int l0 = gl0 % LL;
    const size_t ds = (size_t)LL * 192;

    for (int i = 0; i < 4; i++) {
        int rrow = wv * 4 + i;
        int l = l0 + rrow;
        float ypr[2][2], zpr[2][2];
        float s1 = 0.f, s2 = 0.f;
#pragma unroll
        for (int kk = 0; kk < 2; kk++) {
            int pair = kk * 64 + lane;
            bool act = (kk == 0) || (lane < 32);
            float y0 = 0.f, y1 = 0.f, z0 = 0.f, z1 = 0.f;
            if (act) {
                int cbase = pair * 2;
                size_t off = ((size_t)(b * 4) * LL + l) * 192 + cbase;
                __hip_bfloat162 v0 = *(const __hip_bfloat162*)&y4[off];
                __hip_bfloat162 v1 = *(const __hip_bfloat162*)&y4[off + ds];
                __hip_bfloat162 v2 = *(const __hip_bfloat162*)&y4[off + 2 * ds];
                __hip_bfloat162 v3 = *(const __hip_bfloat162*)&y4[off + 3 * ds];
                y0 = __bfloat162float(v0.x) + __bfloat162float(v1.x)
                   + __bfloat162float(v2.x) + __bfloat162float(v3.x);
                y1 = __bfloat162float(v0.y) + __bfloat162float(v1.y)
                   + __bfloat162float(v2.y) + __bfloat162float(v3.y);
                __hip_bfloat162 zv = *(const __hip_bfloat162*)&zs[((size_t)b * LL + l) * 192 + cbase];
                z0 = __bfloat162float(zv.x);
                z1 = __bfloat162float(zv.y);
                s1 += y0 + y1;
                s2 += y0 * y0 + y1 * y1;
            }
            ypr[kk][0] = y0; ypr[kk][1] = y1;
            zpr[kk][0] = z0; zpr[kk][1] = z1;
        }
#pragma unroll
        for (int o = 32; o; o >>= 1) {
            s1 += __shfl_xor(s1, o, 64);
            s2 += __shfl_xor(s2, o, 64);
        }
        float mean = s1 * (1.f / 192.f);
        float var = s2 * (1.f / 192.f) - mean * mean;
        float rs = rsqrtf(var + 1e-5f);
#pragma unroll
        for (int kk = 0; kk < 2; kk++) {
            bool act = (kk == 0) || (lane < 32);
            if (act) {
                int cbase = (kk * 64 + lane) * 2;
#pragma unroll
                for (int p = 0; p < 2; p++) {
                    int cc = cbase + p;
                    float yn = (ypr[kk][p] - mean) * rs * lng[cc] + lnb[cc];
                    acts[rrow][cc] = yn * zpr[kk][p];
                }
            }
        }
    }

    int ty = tid & 15;
    int tx = tid >> 4;
    v2f o2[3];
    o2[0].x = 0.f; o2[0].y = 0.f;
    o2[1].x = 0.f; o2[1].y = 0.f;
    o2[2].x = 0.f; o2[2].y = 0.f;

    for (int kc = 0; kc < 192; kc += 32) {
        __syncthreads();
        for (int i = tid; i < 32 * 24; i += 256) {
            int d = i / 24, q = i - d * 24;
            *(float4*)&wsh[d][q * 4] = *(const float4*)&Wout[(kc + d) * 96 + q * 4];
        }
        __syncthreads();
#pragma unroll
        for (int kk = 0; kk < 32; kk++) {
            float av = acts[ty][kc + kk];
            const v2f* wp = (const v2f*)&wsh[kk][tx * 6];
            v2f w0 = wp[0], w1 = wp[1], w2 = wp[2];
            v2f sp; sp.x = av; sp.y = av;
            o2[0] += sp * w0;
            o2[1] += sp * w1;
            o2[2] += sp * w2;
        }
    }
    int l = l0 + ty;
#pragma unroll
    for (int j = 0; j < 6; j++) {
        int n = tx * 6 + j;
        out[((size_t)(b * 96) + n) * LL + l] = o2[j >> 1][j & 1];
    }
}

extern "C" void kernel_launch(void* const* d_in, const int* in_sizes, int n_in,
                              void* d_out, int out_size, void* d_ws, size_t ws_size,
                              hipStream_t stream)
{
    const float* x    = (const float*)d_in[0];
    const float* Win  = (const float*)d_in[1];
    const float* bin  = (const float*)d_in[2];
    const float* wdw  = (const float*)d_in[3];
    const float* bdw  = (const float*)d_in[4];
    const float* Alog = (const float*)d_in[5];
    const float* Dp   = (const float*)d_in[6];
    const float* Wx   = (const float*)d_in[7];
    const float* Wd   = (const float*)d_in[8];
    const float* bdl  = (const float*)d_in[9];
    const float* lng  = (const float*)d_in[10];
    const float* lnb  = (const float*)d_in[11];
    const float* Wout = (const float*)d_in[12];
    float* out = (float*)d_out;

    float* ws    = (float*)d_ws;
    __hip_bfloat16* y4 = (__hip_bfloat16*)(ws + F_Y4);
    float* xx    = ws + F_XX;    // aliases y4 slab region (dead before y4 written)
    __hip_bfloat16* zs = (__hip_bfloat16*)(ws + F_ZS);
    float* xt    = ws + F_XT;
    float* xd0   = ws + F_XD0;
    float* xd1   = ws + F_XD1;
    float* xd2   = ws + F_XD2;
    float* xd3   = ws + F_XD3;
    float* Sbuf  = ws + F_SBUF;
    __hip_bfloat16* Hbuf = (__hip_bfloat16*)(ws + F_HBUF);
    float* wcomb = ws + F_WCOMB;
    float* A0f   = ws + F_A0;
    float* Ffl   = ws + F_FF;

    k1_inproj<<<1152, 256, 0, stream>>>(x, Win, bin, Wx, Alog, wcomb, A0f, Ffl, xx, zs);
    k2_conv<<<1152, 192, 0, stream>>>(xx, wdw, bdw, xt);
    k3_xdbl<<<576, 320, 0, stream>>>(xt, wcomb, xd0, xd1, xd2, xd3);
    k4_pass1<<<2304, 192, 0, stream>>>(xt, xd0, xd1, xd2, xd3, Wd, bdl, Alog, A0f, Ffl, Sbuf, Hbuf);
    k4_pass2<<<96, 256, 0, stream>>>(Sbuf, Alog, Hbuf);
    k4_pass3<<<2304, 192, 0, stream>>>(xt, xd0, xd1, xd2, xd3, Wd, bdl, Alog, A0f, Ffl, Dp, Hbuf, y4);
    k5_out<<<1152, 256, 0, stream>>>(y4, zs, lng, lnb, Wout, out);
}